// Round 8
// baseline (323.747 us; speedup 1.0000x reference)
//
#include <hip/hip_runtime.h>
#include <stdint.h>

#define ENC_D 512
#define ATTN_D 512
#define STR_D 256
#define CELL_D 512
#define BATCH 64
#define SEQ 1024
#define NROWS (BATCH * SEQ)

typedef __bf16 bf16x8 __attribute__((ext_vector_type(8)));
typedef float f32x4 __attribute__((ext_vector_type(4)));

__device__ __forceinline__ unsigned short f2bf(float f) {
    unsigned int u = __float_as_uint(f);
    u += 0x7fffu + ((u >> 16) & 1u);   // RNE
    return (unsigned short)(u >> 16);
}

// native-cast bf16x8 pack: compiler emits v_cvt_pk_bf16_f32 (RNE, identical
// numerics to f2bf — verified r5/r6: absmax unchanged) at ~1/4 the VALU cost.
__device__ __forceinline__ bf16x8 cvt8(const float4 a, const float4 b) {
    bf16x8 r;
    r[0] = (__bf16)a.x; r[1] = (__bf16)a.y; r[2] = (__bf16)a.z; r[3] = (__bf16)a.w;
    r[4] = (__bf16)b.x; r[5] = (__bf16)b.y; r[6] = (__bf16)b.z; r[7] = (__bf16)b.w;
    return r;
}

__device__ __forceinline__ void lds_cp16(void* l, const void* g) {
    __builtin_amdgcn_global_load_lds(
        (const __attribute__((address_space(1))) unsigned int*)g,
        (__attribute__((address_space(3))) unsigned int*)l, 16, 0, 0);
}

// Fused waitcnt+barrier as ONE asm with a memory clobber (compiler fence);
// vmcnt(N) leaves the newest prefetch in flight across the barrier.
#define BAR_VM4() asm volatile("s_waitcnt vmcnt(4)\n\ts_barrier" ::: "memory")
#define BAR_VM0() asm volatile("s_waitcnt vmcnt(0)\n\ts_barrier" ::: "memory")

// ---------------------------------------------------------------------------
// Kernel 1 (fused): blocks 0..63   : WF = bf16(W_enc^T) fragment-linear
//                   blocks 64..831 : bias partials [jq][b][a] (12 slabs)
//                   block  832     : zero the 64 per-batch fan-in counters
// WF granule (16 B) = 8 k-elems of one column; gi = nt*1024 + ks*64 + quad*16 + c.
// ---------------------------------------------------------------------------
__global__ __launch_bounds__(256) void k_prep(const float* __restrict__ W,
                                              unsigned short* __restrict__ WF,
                                              const float* __restrict__ str,
                                              const float* __restrict__ cell,
                                              const float* __restrict__ Wstr,
                                              const float* __restrict__ Wcell,
                                              float* __restrict__ bpart,
                                              unsigned int* __restrict__ cnt) {
    __shared__ char smraw[64 * 68 * 2];        // 8704 B, reused per role
    const int bx = blockIdx.x, t = threadIdx.x;

    if (bx < 64) {
        unsigned short* T = (unsigned short*)smraw;   // [n_local][e_local] stride 68
        const int ei = bx >> 3, ni = bx & 7;
        const int e0 = ei * 64, n0 = ni * 64;
#pragma unroll
        for (int i = 0; i < 4; ++i) {
            const int idx = t + i * 256;
            const int r = idx >> 4, c4 = idx & 15;
            const float4 v = *(const float4*)(W + (size_t)(e0 + r) * ATTN_D + n0 + c4 * 4);
            T[(c4 * 4 + 0) * 68 + r] = f2bf(v.x);
            T[(c4 * 4 + 1) * 68 + r] = f2bf(v.y);
            T[(c4 * 4 + 2) * 68 + r] = f2bf(v.z);
            T[(c4 * 4 + 3) * 68 + r] = f2bf(v.w);
        }
        __syncthreads();
#pragma unroll
        for (int i = 0; i < 2; ++i) {
            const int q = t + i * 256;
            const int n = q >> 3, ge = q & 7;
            union { unsigned short s[8]; uint4 u; } o;
#pragma unroll
            for (int j = 0; j < 8; ++j) o.s[j] = T[n * 68 + ge * 8 + j];
            const int ng = n0 + n;
            const int g = ei * 8 + ge;
            const int nt = ng >> 4, c = ng & 15;
            const int ks = g >> 2, quad = g & 3;
            const int gi = nt * 1024 + ks * 64 + quad * 16 + c;
            *(uint4*)(WF + (size_t)gi * 8) = o.u;
        }
    } else if (bx < 832) {
        float* sj = (float*)smraw;          // 64 floats
        float* red = (float*)smraw + 64;    // 512 floats
        const int q = bx - 64;
        const int b = q / 12, jq = q - b * 12;
        const float* hvec;
        const float* Wbase;
        if (jq < 4) { hvec = str + b * STR_D + jq * 64;         Wbase = Wstr + (size_t)(jq * 64) * ATTN_D; }
        else        { hvec = cell + b * CELL_D + (jq - 4) * 64; Wbase = Wcell + (size_t)((jq - 4) * 64) * ATTN_D; }
        if (t < 64) sj[t] = hvec[t];
        __syncthreads();
        const int h = t >> 7, a4 = t & 127;
        f32x4 acc = {0.f, 0.f, 0.f, 0.f};
#pragma unroll 8
        for (int i = h * 32; i < h * 32 + 32; ++i) {
            const float s = sj[i];
            const float4 wv = *(const float4*)(Wbase + (size_t)i * ATTN_D + a4 * 4);
            acc[0] += s * wv.x; acc[1] += s * wv.y; acc[2] += s * wv.z; acc[3] += s * wv.w;
        }
        if (h == 1) *(f32x4*)(red + a4 * 4) = acc;
        __syncthreads();
        if (h == 0) {
            const f32x4 o = *(const f32x4*)(red + a4 * 4);
            acc[0] += o[0]; acc[1] += o[1]; acc[2] += o[2]; acc[3] += o[3];
            *(f32x4*)(bpart + (size_t)(jq * BATCH + b) * ATTN_D + a4 * 4) = acc;
        }
    } else {
        // zero the fan-in counters (runs every graph iteration, before k_scores)
        if (t < BATCH) cnt[t] = 0u;
    }
}

// ---------------------------------------------------------------------------
// Kernel 2: fused scores GEMM + flash partial context + per-batch fan-in
// (r6 structure — best measured). 256 blocks x 512 threads (8 waves),
// M=256/block, M=32/wave, 1 block/CU, 16 chunks of 32 cols, 3-deep 32 KB
// staging ring, vmcnt(4) never-drain ledger.
// r8 changes:
// (1) A-phase register batching: per m-tile, ALL 32 independent float4 loads
//     are issued into named temps, sched_barrier(0), then converted. r6's
//     load->cvt interleave kept only ~8 results live (VGPR 104) => ~8 KB/CU
//     in flight vs the ~9.2 KB needed at 900-cyc HBM latency — the E read ran
//     at <50% BW (r7's LDS attempt hit rule-#20 scratch spill: WRITE 33.8 MB).
//     This is the clean test: ~128 VGPR of temps, no asm, all static indices.
// (2) k_final folded in: each block threadfence+atomicAdd's its batch counter
//     (zeroed by k_prep each iteration); the 4th block re-fences and combines
//     the 4 partials into out directly. Removes one kernel boundary (~10 us).
// ---------------------------------------------------------------------------
__global__ __launch_bounds__(512, 1) void k_scores(const float* __restrict__ E,
                                                   const unsigned short* __restrict__ WF,
                                                   const float* __restrict__ bpart,
                                                   const float* __restrict__ b_enc,
                                                   const float* __restrict__ b_str,
                                                   const float* __restrict__ b_cell,
                                                   const float* __restrict__ Wcomb,
                                                   float* __restrict__ ctxp,
                                                   float* __restrict__ stats,
                                                   unsigned int* __restrict__ cnt,
                                                   float* __restrict__ out) {
    __shared__ unsigned short buf[3][16384];    // 3 x 32 KB
    __shared__ float sbias[512];
    __shared__ float sWc[512];
    __shared__ float sx[256];                   // raw scores of this block's rows
    __shared__ float ex[256];                   // e^(s - m_p)
    __shared__ float red[3][512];               // ctx 4->1 group reduce
    __shared__ float rtmp[8];
    __shared__ int lastf;

    const int tid = threadIdx.x;
    const int r0 = blockIdx.x * 256;
    const int b = blockIdx.x >> 2;              // 4 blocks per batch
    const int w = tid >> 6, lane = tid & 63;
    const int quad = lane >> 4, c = lane & 15;

    // stage chunks 0 and 1 (async, 2 x 32 KB = 4 issues x 512 thr x 16 B each)
#pragma unroll
    for (int p = 0; p < 2; ++p)
#pragma unroll
        for (int i = 0; i < 4; ++i)
            lds_cp16((char*)&buf[p][0] + i * 8192 + tid * 16,
                     (const char*)WF + (size_t)p * 32768 + i * 8192 + tid * 16);

    // bias finalize into LDS (overlaps staging)
    if (tid < 128) {
        const int a = tid * 4;
        const float4 be = *(const float4*)(b_enc + a);
        const float4 bs = *(const float4*)(b_str + a);
        const float4 bc = *(const float4*)(b_cell + a);
        f32x4 s;
        s[0] = be.x + bs.x + bc.x; s[1] = be.y + bs.y + bc.y;
        s[2] = be.z + bs.z + bc.z; s[3] = be.w + bs.w + bc.w;
#pragma unroll
        for (int jq = 0; jq < 12; ++jq) {
            const float4 p = *(const float4*)(bpart + (size_t)(jq * BATCH + b) * ATTN_D + a);
            s[0] += p.x; s[1] += p.y; s[2] += p.z; s[3] += p.w;
        }
        *(f32x4*)(sbias + a) = s;
        const float4 wcv = *(const float4*)(Wcomb + a);
        f32x4 wc4; wc4[0] = wcv.x; wc4[1] = wcv.y; wc4[2] = wcv.z; wc4[3] = wcv.w;
        *(f32x4*)(sWc + a) = wc4;
    }

    // ---- A-phase: 2 m-tiles x full K, register-batched for in-flight depth.
    // Per m-tile: issue ALL 32 independent float4 loads (128 VGPR of temps),
    // sched_barrier(0) pins them above the converts -> 32 loads in flight.
    bf16x8 afr[2][16];
#pragma unroll
    for (int m = 0; m < 2; ++m) {
        const float* Ep = E + (size_t)(r0 + w * 32 + m * 16 + c) * ENC_D + quad * 8;
        float4 t0[16], t1[16];
#pragma unroll
        for (int ks = 0; ks < 16; ++ks) {
            t0[ks] = *(const float4*)(Ep + ks * 32);
            t1[ks] = *(const float4*)(Ep + ks * 32 + 4);
        }
        __builtin_amdgcn_sched_barrier(0);   // loads stay above, cvts below
#pragma unroll
        for (int ks = 0; ks < 16; ++ks)
            afr[m][ks] = cvt8(t0[ks], t1[ks]);
    }

    float sc0[4] = {0.f, 0.f, 0.f, 0.f};
    float sc1[4] = {0.f, 0.f, 0.f, 0.f};

    __syncthreads();   // one full drain: chunks 0,1 staged; sbias/sWc visible

    int cbuf = 0, sbuf = 2;
    for (int ch = 0; ch < 16; ++ch) {
        // issue async staging for chunk ch+2 into the free ring slot
        if (ch < 14) {
            const char* gsrc = (const char*)WF + (size_t)(ch + 2) * 32768;
            char* ldst = (char*)&buf[sbuf][0];
#pragma unroll
            for (int i = 0; i < 4; ++i)
                lds_cp16(ldst + i * 8192 + tid * 16, gsrc + i * 8192 + tid * 16);
        }

        // compute chunk ch: 8 ds_read_b128 per 4-ks batch, then 16 MFMAs
        const unsigned short* wb = &buf[cbuf][0];
        f32x4 a0e = {0.f,0.f,0.f,0.f}, a0o = {0.f,0.f,0.f,0.f};
        f32x4 a1e = {0.f,0.f,0.f,0.f}, a1o = {0.f,0.f,0.f,0.f};
        f32x4 b0e = {0.f,0.f,0.f,0.f}, b0o = {0.f,0.f,0.f,0.f};
        f32x4 b1e = {0.f,0.f,0.f,0.f}, b1o = {0.f,0.f,0.f,0.f};
#pragma unroll
        for (int ks = 0; ks < 16; ks += 4) {
            const bf16x8 f0 = *(const bf16x8*)(wb + ((ks + 0) * 64 + lane) * 8);
            const bf16x8 f1 = *(const bf16x8*)(wb + ((ks + 1) * 64 + lane) * 8);
            const bf16x8 f2 = *(const bf16x8*)(wb + ((ks + 2) * 64 + lane) * 8);
            const bf16x8 f3 = *(const bf16x8*)(wb + ((ks + 3) * 64 + lane) * 8);
            const bf16x8 g0 = *(const bf16x8*)(wb + 8192 + ((ks + 0) * 64 + lane) * 8);
            const bf16x8 g1 = *(const bf16x8*)(wb + 8192 + ((ks + 1) * 64 + lane) * 8);
            const bf16x8 g2 = *(const bf16x8*)(wb + 8192 + ((ks + 2) * 64 + lane) * 8);
            const bf16x8 g3 = *(const bf16x8*)(wb + 8192 + ((ks + 3) * 64 + lane) * 8);
            a0e = __builtin_amdgcn_mfma_f32_16x16x32_bf16(afr[0][ks + 0], f0, a0e, 0, 0, 0);
            a1e = __builtin_amdgcn_mfma_f32_16x16x32_bf16(afr[1][ks + 0], f0, a1e, 0, 0, 0);
            a0o = __builtin_amdgcn_mfma_f32_16x16x32_bf16(afr[0][ks + 1], f1, a0o, 0, 0, 0);
            a1o = __builtin_amdgcn_mfma_f32_16x16x32_bf16(afr[1][ks + 1], f1, a1o, 0, 0, 0);
            b0e = __builtin_amdgcn_mfma_f32_16x16x32_bf16(afr[0][ks + 0], g0, b0e, 0, 0, 0);
            b1e = __builtin_amdgcn_mfma_f32_16x16x32_bf16(afr[1][ks + 0], g0, b1e, 0, 0, 0);
            b0o = __builtin_amdgcn_mfma_f32_16x16x32_bf16(afr[0][ks + 1], g1, b0o, 0, 0, 0);
            b1o = __builtin_amdgcn_mfma_f32_16x16x32_bf16(afr[1][ks + 1], g1, b1o, 0, 0, 0);
            a0e = __builtin_amdgcn_mfma_f32_16x16x32_bf16(afr[0][ks + 2], f2, a0e, 0, 0, 0);
            a1e = __builtin_amdgcn_mfma_f32_16x16x32_bf16(afr[1][ks + 2], f2, a1e, 0, 0, 0);
            a0o = __builtin_amdgcn_mfma_f32_16x16x32_bf16(afr[0][ks + 3], f3, a0o, 0, 0, 0);
            a1o = __builtin_amdgcn_mfma_f32_16x16x32_bf16(afr[1][ks + 3], f3, a1o, 0, 0, 0);
            b0e = __builtin_amdgcn_mfma_f32_16x16x32_bf16(afr[0][ks + 2], g2, b0e, 0, 0, 0);
            b1e = __builtin_amdgcn_mfma_f32_16x16x32_bf16(afr[1][ks + 2], g2, b1e, 0, 0, 0);
            b0o = __builtin_amdgcn_mfma_f32_16x16x32_bf16(afr[0][ks + 3], g3, b0o, 0, 0, 0);
            b1o = __builtin_amdgcn_mfma_f32_16x16x32_bf16(afr[1][ks + 3], g3, b1o, 0, 0, 0);
        }

        // epilogue: bias + relu + dot(W_comb)
        const int n0 = ch * 32 + c;
        const float bi0 = sbias[n0], wc0 = sWc[n0];
        const float bi1 = sbias[n0 + 16], wc1 = sWc[n0 + 16];
#pragma unroll
        for (int r = 0; r < 4; ++r) {
            float v;
            v = (a0e[r] + a0o[r]) + bi0; sc0[r] += (v > 0.f ? v : 0.f) * wc0;
            v = (b0e[r] + b0o[r]) + bi1; sc0[r] += (v > 0.f ? v : 0.f) * wc1;
            v = (a1e[r] + a1o[r]) + bi0; sc1[r] += (v > 0.f ? v : 0.f) * wc0;
            v = (b1e[r] + b1o[r]) + bi1; sc1[r] += (v > 0.f ? v : 0.f) * wc1;
        }

        // rotate ring; fenced barrier keeping the newest prefetch in flight
        cbuf = (cbuf == 2) ? 0 : cbuf + 1;
        sbuf = (sbuf == 2) ? 0 : sbuf + 1;
        if (ch < 15) {
            if (ch < 14) BAR_VM4();
            else         BAR_VM0();
        }
    }

    // reduce across the 16 column-lanes; c==0 lanes hold the row scores
#pragma unroll
    for (int r = 0; r < 4; ++r) {
        float v0 = sc0[r], v1 = sc1[r];
        v0 += __shfl_xor(v0, 1); v1 += __shfl_xor(v1, 1);
        v0 += __shfl_xor(v0, 2); v1 += __shfl_xor(v1, 2);
        v0 += __shfl_xor(v0, 4); v1 += __shfl_xor(v1, 4);
        sc0[r] = v0 + __shfl_xor(v0, 8);
        sc1[r] = v1 + __shfl_xor(v1, 8);
    }
    if (c == 0) {
        const int l0 = w * 32 + quad * 4;
#pragma unroll
        for (int r = 0; r < 4; ++r) sx[l0 + r] = sc0[r];
#pragma unroll
        for (int r = 0; r < 4; ++r) sx[l0 + 16 + r] = sc1[r];
    }
    __syncthreads();

    // ---- block-local softmax partial over this block's 256 rows ----
    if (tid < 256) {
        float v = sx[tid];
        float mm = v;
#pragma unroll
        for (int o = 32; o > 0; o >>= 1) mm = fmaxf(mm, __shfl_xor(mm, o));
        if (lane == 0) rtmp[w] = mm;
    }
    __syncthreads();
    const float m_p = fmaxf(fmaxf(rtmp[0], rtmp[1]), fmaxf(rtmp[2], rtmp[3]));
    if (tid < 256) {
        const float e = __expf(sx[tid] - m_p);
        ex[tid] = e;
        float ss = e;
#pragma unroll
        for (int o = 32; o > 0; o >>= 1) ss += __shfl_xor(ss, o);
        if (lane == 0) rtmp[4 + w] = ss;
    }
    __syncthreads();   // publishes ex[] and partial sums
    if (tid == 0) {
        stats[blockIdx.x * 2 + 0] = m_p;
        stats[blockIdx.x * 2 + 1] = rtmp[4] + rtmp[5] + rtmp[6] + rtmp[7];
    }

    // ---- partial context: ctx_p[512] = sum_l ex[l] * E[r0+l, :] ----
    // 4 row-groups of 64 x 128 col4-threads; E slice re-read f32 (L2/L3-hot).
    {
        const int g = tid >> 7, col4 = tid & 127;
        const float* Ep = E + (size_t)(r0 + g * 64) * ENC_D + col4 * 4;
        f32x4 accA = {0.f, 0.f, 0.f, 0.f};
        f32x4 accB = {0.f, 0.f, 0.f, 0.f};
#pragma unroll 8
        for (int l = 0; l < 64; l += 2) {
            const float4 eA = *(const float4*)(Ep + (size_t)l * ENC_D);
            const float4 eB = *(const float4*)(Ep + (size_t)(l + 1) * ENC_D);
            const float wA = ex[g * 64 + l];
            const float wB = ex[g * 64 + l + 1];
            accA[0] += wA * eA.x; accA[1] += wA * eA.y;
            accA[2] += wA * eA.z; accA[3] += wA * eA.w;
            accB[0] += wB * eB.x; accB[1] += wB * eB.y;
            accB[2] += wB * eB.z; accB[3] += wB * eB.w;
        }
        f32x4 acc;
        acc[0] = accA[0] + accB[0]; acc[1] = accA[1] + accB[1];
        acc[2] = accA[2] + accB[2]; acc[3] = accA[3] + accB[3];
        if (g > 0) *(f32x4*)(&red[g - 1][col4 * 4]) = acc;
        __syncthreads();
        if (g == 0) {
            const f32x4 r1 = *(const f32x4*)(&red[0][col4 * 4]);
            const f32x4 r2 = *(const f32x4*)(&red[1][col4 * 4]);
            const f32x4 r3 = *(const f32x4*)(&red[2][col4 * 4]);
            acc[0] += r1[0] + r2[0] + r3[0];
            acc[1] += r1[1] + r2[1] + r3[1];
            acc[2] += r1[2] + r2[2] + r3[2];
            acc[3] += r1[3] + r2[3] + r3[3];
            *(f32x4*)(ctxp + (size_t)blockIdx.x * 512 + col4 * 4) = acc;
        }
    }

    // ---- fan-in: 4th block of the batch combines (replaces k_final) ----
    // Writers (stats: tid0, ctxp: tid<128) fence their own stores device-wide;
    // syncthreads orders every writer's fence before tid0's counter bump.
    __threadfence();
    __syncthreads();
    if (tid == 0) lastf = (atomicAdd(&cnt[b], 1u) == 3u) ? 1 : 0;
    __syncthreads();
    if (lastf) {
        __threadfence();   // acquire: invalidate stale cache before peer reads
        float mp[4], zp[4];
#pragma unroll
        for (int p = 0; p < 4; ++p) {
            mp[p] = stats[(b * 4 + p) * 2];
            zp[p] = stats[(b * 4 + p) * 2 + 1];
        }
        const float m = fmaxf(fmaxf(mp[0], mp[1]), fmaxf(mp[2], mp[3]));
        float a[4], D = 0.f;
#pragma unroll
        for (int p = 0; p < 4; ++p) { a[p] = __expf(mp[p] - m); D += zp[p] * a[p]; }
        const float invD = 1.f / D;
        float o = 0.f;
#pragma unroll
        for (int p = 0; p < 4; ++p)
            o += ctxp[(size_t)(b * 4 + p) * 512 + tid] * a[p];
        out[(size_t)b * ENC_D + tid] = o * invD;
    }
}

// ---------------------------------------------------------------------------
extern "C" void kernel_launch(void* const* d_in, const int* in_sizes, int n_in,
                              void* d_out, int out_size, void* d_ws, size_t ws_size,
                              hipStream_t stream) {
    const float* E      = (const float*)d_in[0];
    const float* str    = (const float*)d_in[1];
    const float* cell   = (const float*)d_in[2];
    const float* Wenc   = (const float*)d_in[3];
    const float* b_enc  = (const float*)d_in[4];
    const float* Wstr   = (const float*)d_in[5];
    const float* b_str  = (const float*)d_in[6];
    const float* Wcell  = (const float*)d_in[7];
    const float* b_cell = (const float*)d_in[8];
    const float* Wcomb  = (const float*)d_in[9];
    // d_in[10] = b_comb: uniform pre-softmax shift — no effect, skipped.
    float* out = (float*)d_out;

    char* ws = (char*)d_ws;
    unsigned short* WF = (unsigned short*)ws;                       // 512 KB
    float* bpart = (float*)(ws + (512 << 10));                      // 1.5 MB
    float* ctxp  = (float*)(ws + (512 << 10) + (1536 << 10));       // 512 KB
    float* stats = (float*)(ws + (512 << 10) + (2048 << 10));       // 2 KB
    unsigned int* cnt = (unsigned int*)(ws + (512 << 10) + (2048 << 10) + 4096); // 256 B

    k_prep<<<833, 256, 0, stream>>>(Wenc, WF, str, cell, Wstr, Wcell, bpart, cnt);
    k_scores<<<NROWS / 256, 512, 0, stream>>>(E, WF, bpart, b_enc, b_str, b_cell,
                                              Wcomb, ctxp, stats, cnt, out);
}